// Round 4
// baseline (49.123 us; speedup 1.0000x reference)
//
#include <hip/hip_runtime.h>

typedef __bf16 bf16x8 __attribute__((ext_vector_type(8)));
typedef float f32x16 __attribute__((ext_vector_type(16)));
typedef float f32x4 __attribute__((ext_vector_type(4)));

#define S_TOTAL 8192
#define DIM 256
#define BK 32

// Block = (batch, kslice, jhalf): 256x128 partial slice via bf16 MFMA.
// 512 threads = 8 waves (4x2 grid of 64x64 wave tiles, 64 AGPR acc).
// __launch_bounds__(512,4) caps total regs at 128/wave -> 2 blocks/CU =
// two independent barrier groups: one block computes while the other
// stalls on its delivery wait (the R3 bottleneck).
// LDS: double-buffered subtiled bf16, A[4kb][256][8] + B[4kb][128][8] = 24KB/buf.
// One __syncthreads per iter (dbuf). niter = kc/32 = 8.
__global__ __launch_bounds__(512, 4) void opm_partial(
    const float* __restrict__ A, const float* __restrict__ Bm,
    __bf16* __restrict__ dstbf, float* __restrict__ dstf32,
    int split, int kc, float scale)
{
    __shared__ __bf16 ldsA[2][4 * 256 * 8];   // 2 x 16 KB
    __shared__ __bf16 ldsB[2][4 * 128 * 8];   // 2 x 8 KB

    const int tid = threadIdx.x;
    const int w   = tid >> 6;                 // 0..7
    const int l   = tid & 63;
    const int bid = blockIdx.x;
    const int jhalf = bid & 1;
    const int sp    = (bid >> 1) % split;
    const int batch = (bid >> 1) / split;
    const long long base = (long long)batch * S_TOTAL * DIM;
    const int s0 = sp * kc;
    const int wr = w >> 1, wc = w & 1;        // wave position in 4x2 grid
    const int lane31 = l & 31;
    const int hi = l >> 5;
    const int niter = kc / BK;

    // staging roles: wave w stages A rows kb=w&3 (8 s-rows), col-half (w>=4),
    // lane owns A cols {ca, ca+64} and B col cb (within the 128-col j-slice).
    const int kb  = w & 3;
    const int chalf = w >> 2;
    const int ca = chalf * 128 + l;           // A cols: ca, ca+64
    const int cb = chalf * 64 + l;            // B col (slice-local)

    f32x16 acc[2][2] = {};
    float r[24];                              // 16 A + 8 B staged f32

    auto loadreg = [&](int it) {
        const long long srow = base + (long long)(s0 + it * BK + kb * 8) * DIM;
        #pragma unroll
        for (int e = 0; e < 8; ++e) r[e]      = A[srow + e * DIM + ca];
        #pragma unroll
        for (int e = 0; e < 8; ++e) r[8 + e]  = A[srow + e * DIM + ca + 64];
        #pragma unroll
        for (int e = 0; e < 8; ++e) r[16 + e] = Bm[srow + e * DIM + jhalf * 128 + cb];
    };
    auto cvtwrite = [&](int buf) {
        bf16x8 v0, v1, v2;
        #pragma unroll
        for (int e = 0; e < 8; ++e) { v0[e] = (__bf16)r[e]; v1[e] = (__bf16)r[8 + e]; v2[e] = (__bf16)r[16 + e]; }
        *(bf16x8*)&ldsA[buf][(kb * 256 + ca) * 8]      = v0;
        *(bf16x8*)&ldsA[buf][(kb * 256 + ca + 64) * 8] = v1;
        *(bf16x8*)&ldsB[buf][(kb * 128 + cb) * 8]      = v2;
    };
    auto compute = [&](int buf) {
        #pragma unroll
        for (int t = 0; t < 2; ++t) {          // 2 k-tiles of 16 within BK=32
            const int kb0 = t * 2 + hi;
            bf16x8 af[2], bfv[2];
            #pragma unroll
            for (int mi = 0; mi < 2; ++mi)
                af[mi] = *(const bf16x8*)&ldsA[buf][(kb0 * 256 + wr * 64 + mi * 32 + lane31) * 8];
            #pragma unroll
            for (int nj = 0; nj < 2; ++nj)
                bfv[nj] = *(const bf16x8*)&ldsB[buf][(kb0 * 128 + wc * 64 + nj * 32 + lane31) * 8];
            #pragma unroll
            for (int mi = 0; mi < 2; ++mi)
                #pragma unroll
                for (int nj = 0; nj < 2; ++nj)
                    acc[mi][nj] = __builtin_amdgcn_mfma_f32_32x32x16_bf16(
                        af[mi], bfv[nj], acc[mi][nj], 0, 0, 0);
        }
    };

    // prologue
    loadreg(0);
    cvtwrite(0);
    __syncthreads();

    for (int it = 0; it < niter; ++it) {
        const int p = it & 1;
        if (it + 1 < niter) loadreg(it + 1);   // issue early; lands during compute
        __builtin_amdgcn_sched_barrier(0);
        compute(p);
        if (it + 1 < niter) cvtwrite(p ^ 1);   // other buffer: safe, prev iter's barrier passed
        __syncthreads();                        // one barrier per iter
    }

    // epilogue: write 256x128 slice
    const long long obase = (long long)(batch * split + sp) * (256 * 256) + jhalf * 128;
    if (dstf32) {
        float* o = dstf32 + obase;
        #pragma unroll
        for (int mi = 0; mi < 2; ++mi)
        #pragma unroll
        for (int nj = 0; nj < 2; ++nj)
        #pragma unroll
        for (int q = 0; q < 16; ++q) {
            const int row = (q & 3) + 8 * (q >> 2) + 4 * hi;
            const int i = wr * 64 + mi * 32 + row;
            const int j = wc * 64 + nj * 32 + lane31;
            o[i * 256 + j] = acc[mi][nj][q] * scale;
        }
    } else {
        __bf16* o = dstbf + obase;
        #pragma unroll
        for (int mi = 0; mi < 2; ++mi)
        #pragma unroll
        for (int nj = 0; nj < 2; ++nj)
        #pragma unroll
        for (int q = 0; q < 16; ++q) {
            const int row = (q & 3) + 8 * (q >> 2) + 4 * hi;
            const int i = wr * 64 + mi * 32 + row;
            const int j = wc * 64 + nj * 32 + lane31;
            o[i * 256 + j] = (__bf16)(acc[mi][nj][q] * scale);
        }
    }
}

// Sum `split` bf16 partials per batch, scale by 1/8192. bf16x8 (16B) per lane.
__global__ __launch_bounds__(256) void opm_reduce(
    const __bf16* __restrict__ ws, float* __restrict__ out, int split)
{
    const int idx = blockIdx.x * 256 + threadIdx.x;   // 65536 groups of 8 f32
    const int b = idx >> 13;                          // 8192 groups per batch
    const int r = idx & 8191;
    const bf16x8* p = (const bf16x8*)ws + (long long)b * split * 8192 + r;
    float s[8] = {0.f, 0.f, 0.f, 0.f, 0.f, 0.f, 0.f, 0.f};
    for (int sp = 0; sp < split; ++sp) {
        bf16x8 v = p[(long long)sp * 8192];
        #pragma unroll
        for (int e = 0; e < 8; ++e) s[e] += (float)v[e];
    }
    f32x4 lo = { s[0], s[1], s[2], s[3] };
    f32x4 hiv = { s[4], s[5], s[6], s[7] };
    lo  *= (1.0f / 8192.0f);
    hiv *= (1.0f / 8192.0f);
    ((f32x4*)out)[idx * 2]     = lo;
    ((f32x4*)out)[idx * 2 + 1] = hiv;
}

extern "C" void kernel_launch(void* const* d_in, const int* in_sizes, int n_in,
                              void* d_out, int out_size, void* d_ws, size_t ws_size,
                              hipStream_t stream)
{
    (void)in_sizes; (void)n_in; (void)out_size;
    const float* A  = (const float*)d_in[0];
    const float* Bm = (const float*)d_in[1];
    float* out = (float*)d_out;

    int split = 32;
    while (split > 1 && (size_t)8 * split * 65536 * sizeof(__bf16) > ws_size) split >>= 1;

    if (split >= 2) {
        const int kc = S_TOTAL / split;
        opm_partial<<<8 * split * 2, 512, 0, stream>>>(A, Bm, (__bf16*)d_ws, nullptr, split, kc, 1.0f);
        opm_reduce<<<256, 256, 0, stream>>>((const __bf16*)d_ws, out, split);
    } else {
        // tiny-ws fallback: 16 blocks over full K, f32 direct to out
        opm_partial<<<8 * 2, 512, 0, stream>>>(A, Bm, nullptr, out, 1, S_TOTAL, 1.0f / 8192.0f);
    }
}